// Round 9
// baseline (4084.660 us; speedup 1.0000x reference)
//
#include <hip/hip_runtime.h>
#include <hip/hip_bf16.h>

typedef unsigned short u16;
typedef unsigned int u32;
typedef unsigned long long u64;
typedef __attribute__((ext_vector_type(8))) short bf16x8;   // 8 bf16 (4 VGPRs)
typedef __attribute__((ext_vector_type(4))) float f32x4;

#define MFMA(a,b,c) __builtin_amdgcn_mfma_f32_16x16x32_bf16((a),(b),(c),0,0,0)
#define AGENT __HIP_MEMORY_SCOPE_AGENT

// R9: sentinel-first dataflow sync, 128 wgs x 512 threads.
//  - 64 GRU5 wgs (rg 0..7 x cb 0..7: 16 batch rows x 64 h-cols) + 64 GRU6 wgs.
//  - h exchange: tagged u32 words (tag<<16|bf16) via relaxed agent atomics
//    (tags = ground truth; retry loop). Producers publish a per-wg sentinel
//    (step counter) AFTER __syncthreads drains their data stores; consumers
//    spin on 8 sentinels (128 B) instead of re-reading 32 KB tiles.
//  - h5: 4 slots (slot s&3) -> cc5 WAR guard cc5>=8*(t-3), off critical path.
//    h6: 2 slots (peer data-dependency makes WAR safe).
//  - GRU5 loop t=0..511 computes h5[t]; GRU6 loop t=1..513 computes h6[t-1]
//    (t<=512) and dec[t-2] (t>=2). fp32 master h state in regs (2/thread).

__device__ __forceinline__ u16 f2bf(float f) {
    u32 u = __float_as_uint(f);
    u32 r = (u + 0x7fffu + ((u >> 16) & 1u)) >> 16;
    return (u16)r;
}
__device__ __forceinline__ float bf2f(u16 v) { return __uint_as_float(((u32)v) << 16); }
__device__ __forceinline__ float sat01(float x) { return fminf(1.f, fmaxf(0.f, x)); }
__device__ __forceinline__ float ftanh(float x) {
    x = fminf(10.f, fmaxf(-10.f, x));
    float e = __expf(2.f * x);
    return (e - 1.f) / (e + 1.f);
}

__device__ __forceinline__ bf16x8 loadB(const float* __restrict__ M, int k0, int colbase,
                                        int l15, int q8) {
    const float* p = M + (size_t)(k0 + q8) * 1536 + colbase + l15;
    bf16x8 r;
#pragma unroll
    for (int j = 0; j < 8; ++j) r[j] = (short)f2bf(p[(size_t)j * 1536]);
    return r;
}

__device__ __forceinline__ bf16x8 ldsA(const u16* s, int stride, int colbase, int l15, int q8) {
    return *(const bf16x8*)(s + l15 * stride + colbase + q8);
}

__global__ void zero_ws_kernel(u32* ws) {
    int i = blockIdx.x * 256 + threadIdx.x;
    if (i < 397568) ws[i] = 0u;  // h5w[4][128][512] + h6w[2][128][512] + sent5 + sent6 + cc5
}

__global__ void __launch_bounds__(512, 2)
gru_fused(const float* __restrict__ zin, const float* __restrict__ x2,
          const float* __restrict__ msk, const float* __restrict__ dmsk,
          const float* __restrict__ W5, const float* __restrict__ U5,
          const float* __restrict__ bi5, const float* __restrict__ br5,
          const float* __restrict__ W6, const float* __restrict__ U6,
          const float* __restrict__ bi6, const float* __restrict__ br6,
          const float* __restrict__ Wd, const float* __restrict__ bdp,
          float* __restrict__ out, u32* __restrict__ h5w,
          u32* __restrict__ h6w, u32* __restrict__ sent5,
          u32* __restrict__ sent6, u32* __restrict__ cc5)
{
    const int wg = blockIdx.x;
    const bool is6 = wg >= 64;
    const int id = is6 ? wg - 64 : wg;
    const int rg = id >> 3;            // 8 rowgroups x 16 batch rows
    const int cb = id & 7;             // 8 colblocks x 64 h-cols
    const int row0 = rg << 4;
    const int tid = threadIdx.x;
    const int wv = tid >> 6, lane = tid & 63;
    const int l15 = lane & 15, q8 = (lane >> 4) << 3;
    const int gs = wv >> 2;            // 0: z+xh waves, 1: r+ih waves
    const int ctl = wv & 3;            // coltile within the 64-col block

    __shared__ u16 stg[16 * 1032];     // GRU5: rows of 840 (320 x | 512 h); GRU6: 1032 (512 g5 | 512 h6)
    __shared__ float exch[16 * 272];   // 16 C-tiles: u = gate{z0,r1,xh2,ih3}*4 + ctl
    __shared__ float wdl[512];         // dense-head weights (GRU6)

    const int colM = gs * 512 + cb * 64 + ctl * 16;   // z or r gate col
    const int colS = 1024 + cb * 64 + ctl * 16;       // h gate col

    const float* bi = is6 ? bi6 : bi5;
    const float* br = is6 ? br6 : br5;
    const float biasM = bi[colM + l15] + br[colM + l15];
    const float biasS = (gs == 0) ? bi[colS + l15] : br[colS + l15];

    // ---- persistent register B fragments (fp32 -> bf16 once) ----
    bf16x8 Bm[32], Bs[16];
    int nBm, nBs;
    if (!is6) {
        // x-part K=320 (10 tiles) + h-part K=512 (16 tiles)
#pragma unroll
        for (int kt = 0; kt < 10; ++kt) Bm[kt] = loadB(W5, kt * 32, colM, l15, q8);
#pragma unroll
        for (int kt = 0; kt < 16; ++kt) Bm[10 + kt] = loadB(U5, kt * 32, colM, l15, q8);
        if (gs == 0) { nBs = 10;
#pragma unroll
            for (int kt = 0; kt < 10; ++kt) Bs[kt] = loadB(W5, kt * 32, colS, l15, q8);
        } else { nBs = 16;
#pragma unroll
            for (int kt = 0; kt < 16; ++kt) Bs[kt] = loadB(U5, kt * 32, colS, l15, q8);
        }
        nBm = 26;
    } else {
#pragma unroll
        for (int kt = 0; kt < 16; ++kt) Bm[kt] = loadB(W6, kt * 32, colM, l15, q8);
#pragma unroll
        for (int kt = 0; kt < 16; ++kt) Bm[16 + kt] = loadB(U6, kt * 32, colM, l15, q8);
        if (gs == 0) {
#pragma unroll
            for (int kt = 0; kt < 16; ++kt) Bs[kt] = loadB(W6, kt * 32, colS, l15, q8);
        } else {
#pragma unroll
            for (int kt = 0; kt < 16; ++kt) Bs[kt] = loadB(U6, kt * 32, colS, l15, q8);
        }
        nBm = 32; nBs = 16;
        if (tid < 512) wdl[tid] = Wd[tid];   // dense head weights to LDS
    }
    float bdv = bdp[0];

    // fp32 master h state: thread owns (row=tid&15, cols 2*(tid>>4), +1) of its 16x64 tile
    float hold0 = 0.f, hold1 = 0.f;
    const int grow = tid & 15, colpair = tid >> 4;     // colpair 0..31
    const int c0 = colpair * 2, c1 = c0 + 1;

    const int r_ = tid >> 5, cth = tid & 31;  // staging coords: 32 threads per row
    const int b_ = row0 + r_;

    if (!is6) {
        // ================= GRU5: t = 0..511, produce h5[t] =================
        for (int t = 0; t < 512; ++t) {
            // x stage (overlaps sentinel wait)
            float mk = msk[b_ * 512 + t];
#pragma unroll
            for (int i = 0; i < 10; ++i) {
                int c = cth + 32 * i;
                float v = (c < 256) ? zin[b_ * 256 + c]
                                    : x2[(b_ * 512 + t) * 64 + (c - 256)];
                stg[r_ * 840 + c] = f2bf(v * mk);
            }
            // sentinel hint: all 8 producers of h5[t-1] done
            if (tid < 8) {
                while (__hip_atomic_load(&sent5[(rg * 8 + tid) * 32], __ATOMIC_RELAXED, AGENT)
                       < (u32)t)
                    __builtin_amdgcn_s_sleep(1);
            }
            __syncthreads();
            // tagged load h5[t-1] (slot (t-1)&3), expect tag t; single round + verify
            {
                const u64* src = (const u64*)(h5w + ((t + 3) & 3) * 65536) +
                                 (size_t)b_ * 256;
                const u32 exp = (u32)t;
                u64 v[8];
                for (;;) {
                    bool ok = true;
#pragma unroll
                    for (int k = 0; k < 8; ++k)
                        v[k] = __hip_atomic_load(&src[cth + 32 * k], __ATOMIC_RELAXED, AGENT);
#pragma unroll
                    for (int k = 0; k < 8; ++k) {
                        u32 lo = (u32)v[k], hi = (u32)(v[k] >> 32);
                        if (((lo >> 16) != exp) | ((hi >> 16) != exp)) ok = false;
                    }
                    if (ok) break;
                    __builtin_amdgcn_s_sleep(1);
                }
#pragma unroll
                for (int k = 0; k < 8; ++k) {
                    u32 lo = (u32)v[k], hi = (u32)(v[k] >> 32);
                    *(u32*)&stg[r_ * 840 + 320 + 2 * (cth + 32 * k)] =
                        (lo & 0xffffu) | (hi << 16);
                }
            }
            __syncthreads();
            // MFMA: x-part K=320, h-part K=512
            f32x4 a0 = {biasM, biasM, biasM, biasM};
            f32x4 a1 = {biasS, biasS, biasS, biasS};
            if (gs == 0) {  // z + xh
#pragma unroll
                for (int kt = 0; kt < 10; ++kt) {
                    bf16x8 a = ldsA(stg, 840, kt * 32, l15, q8);
                    a0 = MFMA(a, Bm[kt], a0);
                    a1 = MFMA(a, Bs[kt], a1);
                }
#pragma unroll
                for (int kt = 0; kt < 16; ++kt) {
                    bf16x8 a = ldsA(stg, 840, 320 + kt * 32, l15, q8);
                    a0 = MFMA(a, Bm[10 + kt], a0);
                }
            } else {        // r + ih
#pragma unroll
                for (int kt = 0; kt < 10; ++kt) {
                    bf16x8 a = ldsA(stg, 840, kt * 32, l15, q8);
                    a0 = MFMA(a, Bm[kt], a0);
                }
#pragma unroll
                for (int kt = 0; kt < 16; ++kt) {
                    bf16x8 a = ldsA(stg, 840, 320 + kt * 32, l15, q8);
                    a0 = MFMA(a, Bm[10 + kt], a0);
                    a1 = MFMA(a, Bs[kt], a1);
                }
            }
            {   // C-layout: col=lane&15, row=(lane>>4)*4+i
                int uM = gs * 4 + ctl, uS = (2 + gs) * 4 + ctl;
#pragma unroll
                for (int i = 0; i < 4; ++i) {
                    int rr = (lane >> 4) * 4 + i;
                    exch[uM * 272 + rr * 17 + l15] = a0[i];
                    exch[uS * 272 + rr * 17 + l15] = a1[i];
                }
            }
            __syncthreads();
            // gate math (2 adjacent cols/thread), WAR guard, tagged u64 store
            {
                int t0 = c0 >> 4, cc0 = c0 & 15, t1 = c1 >> 4, cc1 = c1 & 15;
                float zv0 = exch[(0 + t0) * 272 + grow * 17 + cc0];
                float zv1 = exch[(0 + t1) * 272 + grow * 17 + cc1];
                float rv0 = exch[(4 + t0) * 272 + grow * 17 + cc0];
                float rv1 = exch[(4 + t1) * 272 + grow * 17 + cc1];
                float xh0 = exch[(8 + t0) * 272 + grow * 17 + cc0];
                float xh1 = exch[(8 + t1) * 272 + grow * 17 + cc1];
                float ih0 = exch[(12 + t0) * 272 + grow * 17 + cc0];
                float ih1 = exch[(12 + t1) * 272 + grow * 17 + cc1];
                float zg0 = sat01(0.2f * zv0 + 0.5f), zg1 = sat01(0.2f * zv1 + 0.5f);
                float rt0 = sat01(0.2f * rv0 + 0.5f), rt1 = sat01(0.2f * rv1 + 0.5f);
                float hh0 = ftanh(xh0 + rt0 * ih0), hh1 = ftanh(xh1 + rt1 * ih1);
                float h0 = zg0 * hold0 + (1.f - zg0) * hh0;
                float h1 = zg1 * hold1 + (1.f - zg1) * hh1;
                hold0 = h0; hold1 = h1;
                if (t >= 4) {   // h5 has 4 slots; GRU6 must have staged h5[t-3]
                    const u32 need = 8u * (u32)(t - 3);
                    while (__hip_atomic_load(&cc5[rg * 32], __ATOMIC_RELAXED, AGENT) < need)
                        __builtin_amdgcn_s_sleep(1);
                }
                const u32 tg = (u32)(t + 1) << 16;
                u64 w = ((u64)(tg | (u32)f2bf(h1)) << 32) | (u64)(tg | (u32)f2bf(h0));
                u64* dst = (u64*)(h5w + (t & 3) * 65536) + (size_t)(row0 + grow) * 256;
                __hip_atomic_store(&dst[(cb * 64 + c0) >> 1], w, __ATOMIC_RELAXED, AGENT);
            }
            __syncthreads();   // drains stores (vmcnt) before sentinel; protects stg
            if (tid == 0)
                __hip_atomic_store(&sent5[(rg * 8 + cb) * 32], (u32)(t + 1),
                                   __ATOMIC_RELAXED, AGENT);
        }
    } else {
        // ============ GRU6: t = 1..513, produce h6[t-1], dec[t-2] ============
        for (int t = 1; t <= 513; ++t) {
            if (t <= 512 && tid < 8) {
                while (__hip_atomic_load(&sent5[(rg * 8 + tid) * 32], __ATOMIC_RELAXED, AGENT)
                       < (u32)t)
                    __builtin_amdgcn_s_sleep(1);
            }
            if (tid >= 64 && tid < 72) {
                while (__hip_atomic_load(&sent6[(rg * 8 + tid - 64) * 32], __ATOMIC_RELAXED, AGENT)
                       < (u32)(t - 1))
                    __builtin_amdgcn_s_sleep(1);
            }
            __syncthreads();
            // tagged loads: g5 = h5[t-1] (tag t, slot (t-1)&3); h6[t-2] (tag t-1, slot t&1)
            if (t <= 512) {
                const u64* s1 = (const u64*)(h5w + ((t + 3) & 3) * 65536) + (size_t)b_ * 256;
                const u32 exp = (u32)t;
                u64 v[8];
                for (;;) {
                    bool ok = true;
#pragma unroll
                    for (int k = 0; k < 8; ++k)
                        v[k] = __hip_atomic_load(&s1[cth + 32 * k], __ATOMIC_RELAXED, AGENT);
#pragma unroll
                    for (int k = 0; k < 8; ++k) {
                        u32 lo = (u32)v[k], hi = (u32)(v[k] >> 32);
                        if (((lo >> 16) != exp) | ((hi >> 16) != exp)) ok = false;
                    }
                    if (ok) break;
                    __builtin_amdgcn_s_sleep(1);
                }
#pragma unroll
                for (int k = 0; k < 8; ++k) {
                    u32 lo = (u32)v[k], hi = (u32)(v[k] >> 32);
                    *(u32*)&stg[r_ * 1032 + 2 * (cth + 32 * k)] = (lo & 0xffffu) | (hi << 16);
                }
            }
            {
                const u64* s2 = (const u64*)(h6w + (t & 1) * 65536) + (size_t)b_ * 256;
                const u32 exp = (u32)(t - 1);
                u64 v[8];
                for (;;) {
                    bool ok = true;
#pragma unroll
                    for (int k = 0; k < 8; ++k)
                        v[k] = __hip_atomic_load(&s2[cth + 32 * k], __ATOMIC_RELAXED, AGENT);
#pragma unroll
                    for (int k = 0; k < 8; ++k) {
                        u32 lo = (u32)v[k], hi = (u32)(v[k] >> 32);
                        if (((lo >> 16) != exp) | ((hi >> 16) != exp)) ok = false;
                    }
                    if (ok) break;
                    __builtin_amdgcn_s_sleep(1);
                }
#pragma unroll
                for (int k = 0; k < 8; ++k) {
                    u32 lo = (u32)v[k], hi = (u32)(v[k] >> 32);
                    *(u32*)&stg[r_ * 1032 + 512 + 2 * (cth + 32 * k)] =
                        (lo & 0xffffu) | (hi << 16);
                }
            }
            __syncthreads();
            if (t <= 512 && tid == 0)   // consumption signal: h5[t-1] staged
                __hip_atomic_fetch_add(&cc5[rg * 32], 1u, __ATOMIC_RELAXED, AGENT);
            if (t <= 512) {
                f32x4 a0 = {biasM, biasM, biasM, biasM};
                f32x4 a1 = {biasS, biasS, biasS, biasS};
                if (gs == 0) {  // z + xh
#pragma unroll
                    for (int kt = 0; kt < 16; ++kt) {
                        bf16x8 a = ldsA(stg, 1032, kt * 32, l15, q8);
                        a0 = MFMA(a, Bm[kt], a0);
                        a1 = MFMA(a, Bs[kt], a1);
                    }
#pragma unroll
                    for (int kt = 0; kt < 16; ++kt) {
                        bf16x8 a = ldsA(stg, 1032, 512 + kt * 32, l15, q8);
                        a0 = MFMA(a, Bm[16 + kt], a0);
                    }
                } else {        // r + ih
#pragma unroll
                    for (int kt = 0; kt < 16; ++kt) {
                        bf16x8 a = ldsA(stg, 1032, kt * 32, l15, q8);
                        a0 = MFMA(a, Bm[kt], a0);
                    }
#pragma unroll
                    for (int kt = 0; kt < 16; ++kt) {
                        bf16x8 a = ldsA(stg, 1032, 512 + kt * 32, l15, q8);
                        a0 = MFMA(a, Bm[16 + kt], a0);
                        a1 = MFMA(a, Bs[kt], a1);
                    }
                }
                {
                    int uM = gs * 4 + ctl, uS = (2 + gs) * 4 + ctl;
#pragma unroll
                    for (int i = 0; i < 4; ++i) {
                        int rr = (lane >> 4) * 4 + i;
                        exch[uM * 272 + rr * 17 + l15] = a0[i];
                        exch[uS * 272 + rr * 17 + l15] = a1[i];
                    }
                }
                __syncthreads();
                {
                    int t0 = c0 >> 4, cc0 = c0 & 15, t1 = c1 >> 4, cc1 = c1 & 15;
                    float zv0 = exch[(0 + t0) * 272 + grow * 17 + cc0];
                    float zv1 = exch[(0 + t1) * 272 + grow * 17 + cc1];
                    float rv0 = exch[(4 + t0) * 272 + grow * 17 + cc0];
                    float rv1 = exch[(4 + t1) * 272 + grow * 17 + cc1];
                    float xh0 = exch[(8 + t0) * 272 + grow * 17 + cc0];
                    float xh1 = exch[(8 + t1) * 272 + grow * 17 + cc1];
                    float ih0 = exch[(12 + t0) * 272 + grow * 17 + cc0];
                    float ih1 = exch[(12 + t1) * 272 + grow * 17 + cc1];
                    float zg0 = sat01(0.2f * zv0 + 0.5f), zg1 = sat01(0.2f * zv1 + 0.5f);
                    float rt0 = sat01(0.2f * rv0 + 0.5f), rt1 = sat01(0.2f * rv1 + 0.5f);
                    float hh0 = ftanh(xh0 + rt0 * ih0), hh1 = ftanh(xh1 + rt1 * ih1);
                    float h0 = zg0 * hold0 + (1.f - zg0) * hh0;
                    float h1 = zg1 * hold1 + (1.f - zg1) * hh1;
                    hold0 = h0; hold1 = h1;
                    const u32 tg = (u32)t << 16;   // h6[t-1] tag = t
                    u64 w = ((u64)(tg | (u32)f2bf(h1)) << 32) | (u64)(tg | (u32)f2bf(h0));
                    u64* dst = (u64*)(h6w + ((t + 1) & 1) * 65536) + (size_t)(row0 + grow) * 256;
                    __hip_atomic_store(&dst[(cb * 64 + c0) >> 1], w, __ATOMIC_RELAXED, AGENT);
                }
            }
            // dec[t-2] from staged h6[t-2] (wave 0; this wg covers rows 2cb, 2cb+1)
            if (t >= 2 && wv == 0) {
                int rw = lane >> 5;                       // 0,1
                int rdec = 2 * cb + rw;
                int kb = (lane & 31) * 16;
                float s = 0.f;
#pragma unroll
                for (int j = 0; j < 16; ++j)
                    s += bf2f(stg[rdec * 1032 + 512 + kb + j]) * wdl[kb + j];
#pragma unroll
                for (int off = 16; off >= 1; off >>= 1)
                    s += __shfl_down(s, off, 32);
                if ((lane & 31) == 0) {
                    int bb = row0 + rdec, tt = t - 2;
                    out[bb * 512 + tt] = ftanh(s + bdv) * dmsk[bb * 512 + tt];
                }
            }
            __syncthreads();   // drains stores before sentinel; protects stg
            if (t <= 512 && tid == 0)
                __hip_atomic_store(&sent6[(rg * 8 + cb) * 32], (u32)t,
                                   __ATOMIC_RELAXED, AGENT);
        }
    }
}

extern "C" void kernel_launch(void* const* d_in, const int* in_sizes, int n_in,
                              void* d_out, int out_size, void* d_ws, size_t ws_size,
                              hipStream_t stream) {
    const float* zin = (const float*)d_in[0];
    const float* x2  = (const float*)d_in[1];
    const float* msk = (const float*)d_in[2];
    const float* dmk = (const float*)d_in[3];
    const float* W5  = (const float*)d_in[4];
    const float* U5  = (const float*)d_in[5];
    const float* bi5 = (const float*)d_in[6];
    const float* br5 = (const float*)d_in[7];
    const float* W6  = (const float*)d_in[8];
    const float* U6  = (const float*)d_in[9];
    const float* bi6 = (const float*)d_in[10];
    const float* br6 = (const float*)d_in[11];
    const float* Wd  = (const float*)d_in[12];
    const float* bd  = (const float*)d_in[13];
    float* out = (float*)d_out;

    // ws (u32 units): h5w[4][128][512] | h6w[2][128][512] | sent5[64*32] | sent6[64*32] | cc5
    u32* h5w = (u32*)d_ws;                 // 1 MB
    u32* h6w = h5w + 262144;               // 512 KB
    u32* sent5 = h6w + 131072;             // 8 KB
    u32* sent6 = sent5 + 2048;             // 8 KB
    u32* cc5 = sent6 + 2048;               // 1 KB

    zero_ws_kernel<<<dim3(1553), dim3(256), 0, stream>>>((u32*)d_ws);

    gru_fused<<<dim3(128), dim3(512), 0, stream>>>(
        zin, x2, msk, dmk, W5, U5, bi5, br5, W6, U6, bi6, br6,
        Wd, bd, out, h5w, h6w, sent5, sent6, cc5);
}

// Round 10
// 3529.159 us; speedup vs baseline: 1.1574x; 1.1574x over previous
//
#include <hip/hip_runtime.h>
#include <hip/hip_bf16.h>

typedef unsigned short u16;
typedef unsigned int u32;
typedef unsigned long long u64;
typedef __attribute__((ext_vector_type(8))) short bf16x8;   // 8 bf16 (4 VGPRs)
typedef __attribute__((ext_vector_type(4))) float f32x4;

#define MFMA(a,b,c) __builtin_amdgcn_mfma_f32_16x16x32_bf16((a),(b),(c),0,0,0)
#define AGENT __HIP_MEMORY_SCOPE_AGENT

// R10 = R8's direct tagged-data polling (1 IC round-trip per hop) with R9's
// halved fan-in (8 producers/rowgroup), spill-free VGPRs, and poll/MFMA overlap.
//  - 128 wgs x 512 threads, __launch_bounds__(512,1) (B-frags need ~200 VGPR).
//  - 64 GRU5 wgs (rg 0..7 x cb 0..7: 16 batch rows x 64 h-cols) + 64 GRU6 wgs.
//  - h words: u32 = (step_tag<<16)|bf16, relaxed agent atomics; tag mismatch
//    => retry. h5: 4 slots (WAR guard cc5 >= 8*(t-3), 3-step slack);
//    h6: 2 slots (WAR safe via peer data dependency).
//  - GRU5 t=0..511 computes h5[t]; GRU6 t=1..513 computes h6[t-1] (t<=512),
//    dec[t-2] (t>=2). fp32 master h state in regs (2 cols/thread).
//  - GRU5 overlap: issue h-poll loads, run x-part MFMAs (K=320, h-independent)
//    under their latency, then tag-check.

__device__ __forceinline__ u16 f2bf(float f) {
    u32 u = __float_as_uint(f);
    u32 r = (u + 0x7fffu + ((u >> 16) & 1u)) >> 16;
    return (u16)r;
}
__device__ __forceinline__ float bf2f(u16 v) { return __uint_as_float(((u32)v) << 16); }
__device__ __forceinline__ float sat01(float x) { return fminf(1.f, fmaxf(0.f, x)); }
__device__ __forceinline__ float ftanh(float x) {
    x = fminf(10.f, fmaxf(-10.f, x));
    float e = __expf(2.f * x);
    return (e - 1.f) / (e + 1.f);
}

__device__ __forceinline__ bf16x8 loadB(const float* __restrict__ M, int k0, int colbase,
                                        int l15, int q8) {
    const float* p = M + (size_t)(k0 + q8) * 1536 + colbase + l15;
    bf16x8 r;
#pragma unroll
    for (int j = 0; j < 8; ++j) r[j] = (short)f2bf(p[(size_t)j * 1536]);
    return r;
}

__device__ __forceinline__ bf16x8 ldsA(const u16* s, int stride, int colbase, int l15, int q8) {
    return *(const bf16x8*)(s + l15 * stride + colbase + q8);
}

__global__ void zero_ws_kernel(u32* ws) {
    int i = blockIdx.x * 256 + threadIdx.x;
    if (i < 393728) ws[i] = 0u;  // h5w[4][128][512] + h6w[2][128][512] + cc5
}

__global__ void __launch_bounds__(512, 1)
gru_fused(const float* __restrict__ zin, const float* __restrict__ x2,
          const float* __restrict__ msk, const float* __restrict__ dmsk,
          const float* __restrict__ W5, const float* __restrict__ U5,
          const float* __restrict__ bi5, const float* __restrict__ br5,
          const float* __restrict__ W6, const float* __restrict__ U6,
          const float* __restrict__ bi6, const float* __restrict__ br6,
          const float* __restrict__ Wd, const float* __restrict__ bdp,
          float* __restrict__ out, u32* __restrict__ h5w,
          u32* __restrict__ h6w, u32* __restrict__ cc5)
{
    const int wg = blockIdx.x;
    const bool is6 = wg >= 64;
    const int id = is6 ? wg - 64 : wg;
    const int rg = id >> 3;            // 8 rowgroups x 16 batch rows
    const int cb = id & 7;             // 8 colblocks x 64 h-cols
    const int row0 = rg << 4;
    const int tid = threadIdx.x;
    const int wv = tid >> 6, lane = tid & 63;
    const int l15 = lane & 15, q8 = (lane >> 4) << 3;
    const int gs = wv >> 2;            // 0: z+xh waves, 1: r+ih waves
    const int ctl = wv & 3;            // coltile (16 cols) within the 64-col block

    __shared__ u16 stg[16 * 1032];     // GRU5 rows of 840 (320 x | 512 h); GRU6 rows of 1032
    __shared__ float exch[16 * 272];   // 16 C-tiles: z:0-3, r:4-7, xh:8-11, ih:12-15 (+ctl)
    __shared__ float wdl[512];         // dense-head weights (GRU6)

    const int colM = gs * 512 + cb * 64 + ctl * 16;
    const int colS = 1024 + cb * 64 + ctl * 16;

    const float* bi = is6 ? bi6 : bi5;
    const float* br = is6 ? br6 : br5;
    const float biasM = bi[colM + l15] + br[colM + l15];
    const float biasS = (gs == 0) ? bi[colS + l15] : br[colS + l15];

    // ---- persistent register B fragments (fp32 -> bf16 once) ----
    bf16x8 Bm[32], Bs[16];
    if (!is6) {
#pragma unroll
        for (int kt = 0; kt < 10; ++kt) Bm[kt] = loadB(W5, kt * 32, colM, l15, q8);
#pragma unroll
        for (int kt = 0; kt < 16; ++kt) Bm[10 + kt] = loadB(U5, kt * 32, colM, l15, q8);
        if (gs == 0) {
#pragma unroll
            for (int kt = 0; kt < 10; ++kt) Bs[kt] = loadB(W5, kt * 32, colS, l15, q8);
        } else {
#pragma unroll
            for (int kt = 0; kt < 16; ++kt) Bs[kt] = loadB(U5, kt * 32, colS, l15, q8);
        }
    } else {
#pragma unroll
        for (int kt = 0; kt < 16; ++kt) Bm[kt] = loadB(W6, kt * 32, colM, l15, q8);
#pragma unroll
        for (int kt = 0; kt < 16; ++kt) Bm[16 + kt] = loadB(U6, kt * 32, colM, l15, q8);
        if (gs == 0) {
#pragma unroll
            for (int kt = 0; kt < 16; ++kt) Bs[kt] = loadB(W6, kt * 32, colS, l15, q8);
        } else {
#pragma unroll
            for (int kt = 0; kt < 16; ++kt) Bs[kt] = loadB(U6, kt * 32, colS, l15, q8);
        }
        wdl[tid] = Wd[tid];
    }
    const float bdv = bdp[0];

    // fp32 master h state: thread owns (row=tid&15, cols c0=2*(tid>>4), c0+1)
    float hold0 = 0.f, hold1 = 0.f;
    const int grow = tid & 15, colpair = tid >> 4;     // colpair 0..31
    const int c0 = colpair * 2, c1 = c0 + 1;

    const int r_ = tid >> 5, cth = tid & 31;  // staging coords: 32 threads/row
    const int b_ = row0 + r_;

    if (!is6) {
        // ================= GRU5: t = 0..511, produce h5[t] =================
        for (int t = 0; t < 512; ++t) {
            // ---- stage masked x ----
            float mk = msk[b_ * 512 + t];
#pragma unroll
            for (int i = 0; i < 10; ++i) {
                int c = cth + 32 * i;
                float v = (c < 256) ? zin[b_ * 256 + c]
                                    : x2[(b_ * 512 + t) * 64 + (c - 256)];
                stg[r_ * 840 + c] = f2bf(v * mk);
            }
            __syncthreads();                       // S1: x staged
            // ---- issue h5[t-1] poll loads (slot (t-1)&3, tag t) ----
            const u64* src = (const u64*)(h5w + ((t + 3) & 3) * 65536) + (size_t)b_ * 256;
            const u32 exp = (u32)t;
            u64 v[8];
#pragma unroll
            for (int k = 0; k < 8; ++k)
                v[k] = __hip_atomic_load(&src[cth + 32 * k], __ATOMIC_RELAXED, AGENT);
            // ---- x-part MFMAs under the load latency ----
            f32x4 a0 = {biasM, biasM, biasM, biasM};
            f32x4 a1 = {biasS, biasS, biasS, biasS};
            if (gs == 0) {
#pragma unroll
                for (int kt = 0; kt < 10; ++kt) {
                    bf16x8 a = ldsA(stg, 840, kt * 32, l15, q8);
                    a0 = MFMA(a, Bm[kt], a0);
                    a1 = MFMA(a, Bs[kt], a1);
                }
            } else {
#pragma unroll
                for (int kt = 0; kt < 10; ++kt) {
                    bf16x8 a = ldsA(stg, 840, kt * 32, l15, q8);
                    a0 = MFMA(a, Bm[kt], a0);
                }
            }
            // ---- tag check / retry ----
            for (;;) {
                bool ok = true;
#pragma unroll
                for (int k = 0; k < 8; ++k) {
                    u32 lo = (u32)v[k], hi = (u32)(v[k] >> 32);
                    if (((lo >> 16) != exp) | ((hi >> 16) != exp)) ok = false;
                }
                if (ok) break;
                __builtin_amdgcn_s_sleep(1);
#pragma unroll
                for (int k = 0; k < 8; ++k)
                    v[k] = __hip_atomic_load(&src[cth + 32 * k], __ATOMIC_RELAXED, AGENT);
            }
#pragma unroll
            for (int k = 0; k < 8; ++k) {
                u32 lo = (u32)v[k], hi = (u32)(v[k] >> 32);
                *(u32*)&stg[r_ * 840 + 320 + 2 * (cth + 32 * k)] = (lo & 0xffffu) | (hi << 16);
            }
            __syncthreads();                       // S2: h staged
            // ---- h-part MFMAs (K=512) ----
            if (gs == 0) {
#pragma unroll
                for (int kt = 0; kt < 16; ++kt) {
                    bf16x8 a = ldsA(stg, 840, 320 + kt * 32, l15, q8);
                    a0 = MFMA(a, Bm[10 + kt], a0);
                }
            } else {
#pragma unroll
                for (int kt = 0; kt < 16; ++kt) {
                    bf16x8 a = ldsA(stg, 840, 320 + kt * 32, l15, q8);
                    a0 = MFMA(a, Bm[10 + kt], a0);
                    a1 = MFMA(a, Bs[kt], a1);
                }
            }
            {   // C-layout: col=lane&15, row=(lane>>4)*4+i
                int uM = gs * 4 + ctl, uS = (2 + gs) * 4 + ctl;
#pragma unroll
                for (int i = 0; i < 4; ++i) {
                    int rr = (lane >> 4) * 4 + i;
                    exch[uM * 272 + rr * 17 + l15] = a0[i];
                    exch[uS * 272 + rr * 17 + l15] = a1[i];
                }
            }
            __syncthreads();                       // S3: exch ready
            // ---- gate math, WAR guard, tagged store ----
            {
                int t0 = c0 >> 4, cc0 = c0 & 15, t1 = c1 >> 4, cc1 = c1 & 15;
                float zv0 = exch[(0 + t0) * 272 + grow * 17 + cc0];
                float zv1 = exch[(0 + t1) * 272 + grow * 17 + cc1];
                float rv0 = exch[(4 + t0) * 272 + grow * 17 + cc0];
                float rv1 = exch[(4 + t1) * 272 + grow * 17 + cc1];
                float xh0 = exch[(8 + t0) * 272 + grow * 17 + cc0];
                float xh1 = exch[(8 + t1) * 272 + grow * 17 + cc1];
                float ih0 = exch[(12 + t0) * 272 + grow * 17 + cc0];
                float ih1 = exch[(12 + t1) * 272 + grow * 17 + cc1];
                float zg0 = sat01(0.2f * zv0 + 0.5f), zg1 = sat01(0.2f * zv1 + 0.5f);
                float rt0 = sat01(0.2f * rv0 + 0.5f), rt1 = sat01(0.2f * rv1 + 0.5f);
                float hh0 = ftanh(xh0 + rt0 * ih0), hh1 = ftanh(xh1 + rt1 * ih1);
                float h0 = zg0 * hold0 + (1.f - zg0) * hh0;
                float h1 = zg1 * hold1 + (1.f - zg1) * hh1;
                hold0 = h0; hold1 = h1;
                if (t >= 4) {   // 4 slots: GRU6 must have staged h5[t-3]
                    const u32 need = 8u * (u32)(t - 3);
                    while (__hip_atomic_load(&cc5[rg * 32], __ATOMIC_RELAXED, AGENT) < need)
                        __builtin_amdgcn_s_sleep(1);
                }
                const u32 tg = (u32)(t + 1) << 16;
                u64 w = ((u64)(tg | (u32)f2bf(h1)) << 32) | (u64)(tg | (u32)f2bf(h0));
                u64* dst = (u64*)(h5w + (t & 3) * 65536) + (size_t)(row0 + grow) * 256;
                __hip_atomic_store(&dst[cb * 32 + colpair], w, __ATOMIC_RELAXED, AGENT);
            }
        }
    } else {
        // ============ GRU6: t = 1..513, produce h6[t-1], dec[t-2] ============
        for (int t = 1; t <= 513; ++t) {
            // ---- poll g5 = h5[t-1] (tag t, slot (t-1)&3) and h6[t-2] (tag t-1, slot t&1) ----
            const u64* s2 = (const u64*)(h6w + (t & 1) * 65536) + (size_t)b_ * 256;
            const u32 exp2 = (u32)(t - 1);
            u64 v1[8], v2[8];
            if (t <= 512) {
                const u64* s1 = (const u64*)(h5w + ((t + 3) & 3) * 65536) + (size_t)b_ * 256;
                const u32 exp1 = (u32)t;
#pragma unroll
                for (int k = 0; k < 8; ++k) {
                    v1[k] = __hip_atomic_load(&s1[cth + 32 * k], __ATOMIC_RELAXED, AGENT);
                    v2[k] = __hip_atomic_load(&s2[cth + 32 * k], __ATOMIC_RELAXED, AGENT);
                }
                for (;;) {
                    bool ok = true;
#pragma unroll
                    for (int k = 0; k < 8; ++k) {
                        u32 lo1 = (u32)v1[k], hi1 = (u32)(v1[k] >> 32);
                        u32 lo2 = (u32)v2[k], hi2 = (u32)(v2[k] >> 32);
                        if (((lo1 >> 16) != exp1) | ((hi1 >> 16) != exp1) |
                            ((lo2 >> 16) != exp2) | ((hi2 >> 16) != exp2)) ok = false;
                    }
                    if (ok) break;
                    __builtin_amdgcn_s_sleep(1);
#pragma unroll
                    for (int k = 0; k < 8; ++k) {
                        v1[k] = __hip_atomic_load(&s1[cth + 32 * k], __ATOMIC_RELAXED, AGENT);
                        v2[k] = __hip_atomic_load(&s2[cth + 32 * k], __ATOMIC_RELAXED, AGENT);
                    }
                }
#pragma unroll
                for (int k = 0; k < 8; ++k) {
                    u32 lo = (u32)v1[k], hi = (u32)(v1[k] >> 32);
                    *(u32*)&stg[r_ * 1032 + 2 * (cth + 32 * k)] = (lo & 0xffffu) | (hi << 16);
                    lo = (u32)v2[k]; hi = (u32)(v2[k] >> 32);
                    *(u32*)&stg[r_ * 1032 + 512 + 2 * (cth + 32 * k)] = (lo & 0xffffu) | (hi << 16);
                }
            } else {  // t == 513: only h6[511] needed (for dec)
#pragma unroll
                for (int k = 0; k < 8; ++k)
                    v2[k] = __hip_atomic_load(&s2[cth + 32 * k], __ATOMIC_RELAXED, AGENT);
                for (;;) {
                    bool ok = true;
#pragma unroll
                    for (int k = 0; k < 8; ++k) {
                        u32 lo = (u32)v2[k], hi = (u32)(v2[k] >> 32);
                        if (((lo >> 16) != exp2) | ((hi >> 16) != exp2)) ok = false;
                    }
                    if (ok) break;
                    __builtin_amdgcn_s_sleep(1);
#pragma unroll
                    for (int k = 0; k < 8; ++k)
                        v2[k] = __hip_atomic_load(&s2[cth + 32 * k], __ATOMIC_RELAXED, AGENT);
                }
#pragma unroll
                for (int k = 0; k < 8; ++k) {
                    u32 lo = (u32)v2[k], hi = (u32)(v2[k] >> 32);
                    *(u32*)&stg[r_ * 1032 + 512 + 2 * (cth + 32 * k)] = (lo & 0xffffu) | (hi << 16);
                }
            }
            __syncthreads();
            if (t <= 512 && tid == 0)   // consumption signal: h5[t-1] staged
                __hip_atomic_fetch_add(&cc5[rg * 32], 1u, __ATOMIC_RELAXED, AGENT);
            if (t <= 512) {
                f32x4 a0 = {biasM, biasM, biasM, biasM};
                f32x4 a1 = {biasS, biasS, biasS, biasS};
                if (gs == 0) {
#pragma unroll
                    for (int kt = 0; kt < 16; ++kt) {
                        bf16x8 a = ldsA(stg, 1032, kt * 32, l15, q8);
                        a0 = MFMA(a, Bm[kt], a0);
                        a1 = MFMA(a, Bs[kt], a1);
                    }
#pragma unroll
                    for (int kt = 0; kt < 16; ++kt) {
                        bf16x8 a = ldsA(stg, 1032, 512 + kt * 32, l15, q8);
                        a0 = MFMA(a, Bm[16 + kt], a0);
                    }
                } else {
#pragma unroll
                    for (int kt = 0; kt < 16; ++kt) {
                        bf16x8 a = ldsA(stg, 1032, kt * 32, l15, q8);
                        a0 = MFMA(a, Bm[kt], a0);
                    }
#pragma unroll
                    for (int kt = 0; kt < 16; ++kt) {
                        bf16x8 a = ldsA(stg, 1032, 512 + kt * 32, l15, q8);
                        a0 = MFMA(a, Bm[16 + kt], a0);
                        a1 = MFMA(a, Bs[kt], a1);
                    }
                }
                {
                    int uM = gs * 4 + ctl, uS = (2 + gs) * 4 + ctl;
#pragma unroll
                    for (int i = 0; i < 4; ++i) {
                        int rr = (lane >> 4) * 4 + i;
                        exch[uM * 272 + rr * 17 + l15] = a0[i];
                        exch[uS * 272 + rr * 17 + l15] = a1[i];
                    }
                }
                __syncthreads();
                {
                    int t0 = c0 >> 4, cc0 = c0 & 15, t1 = c1 >> 4, cc1 = c1 & 15;
                    float zv0 = exch[(0 + t0) * 272 + grow * 17 + cc0];
                    float zv1 = exch[(0 + t1) * 272 + grow * 17 + cc1];
                    float rv0 = exch[(4 + t0) * 272 + grow * 17 + cc0];
                    float rv1 = exch[(4 + t1) * 272 + grow * 17 + cc1];
                    float xh0 = exch[(8 + t0) * 272 + grow * 17 + cc0];
                    float xh1 = exch[(8 + t1) * 272 + grow * 17 + cc1];
                    float ih0 = exch[(12 + t0) * 272 + grow * 17 + cc0];
                    float ih1 = exch[(12 + t1) * 272 + grow * 17 + cc1];
                    float zg0 = sat01(0.2f * zv0 + 0.5f), zg1 = sat01(0.2f * zv1 + 0.5f);
                    float rt0 = sat01(0.2f * rv0 + 0.5f), rt1 = sat01(0.2f * rv1 + 0.5f);
                    float hh0 = ftanh(xh0 + rt0 * ih0), hh1 = ftanh(xh1 + rt1 * ih1);
                    float h0 = zg0 * hold0 + (1.f - zg0) * hh0;
                    float h1 = zg1 * hold1 + (1.f - zg1) * hh1;
                    hold0 = h0; hold1 = h1;
                    const u32 tg = (u32)t << 16;   // h6[t-1] tag = t
                    u64 w = ((u64)(tg | (u32)f2bf(h1)) << 32) | (u64)(tg | (u32)f2bf(h0));
                    u64* dst = (u64*)(h6w + ((t + 1) & 1) * 65536) + (size_t)(row0 + grow) * 256;
                    __hip_atomic_store(&dst[cb * 32 + colpair], w, __ATOMIC_RELAXED, AGENT);
                }
            }
            // dec[t-2] from staged h6[t-2] (wave 0; rows 2cb, 2cb+1)
            if (t >= 2 && wv == 0) {
                int rdec = 2 * cb + (lane >> 5);
                int kb = (lane & 31) * 16;
                float s = 0.f;
#pragma unroll
                for (int j = 0; j < 16; ++j)
                    s += bf2f(stg[rdec * 1032 + 512 + kb + j]) * wdl[kb + j];
#pragma unroll
                for (int off = 16; off >= 1; off >>= 1)
                    s += __shfl_down(s, off, 32);
                if ((lane & 31) == 0) {
                    int bb = row0 + rdec, tt = t - 2;
                    out[bb * 512 + tt] = ftanh(s + bdv) * dmsk[bb * 512 + tt];
                }
            }
            __syncthreads();   // protect stg before next iteration's writes
        }
    }
}

extern "C" void kernel_launch(void* const* d_in, const int* in_sizes, int n_in,
                              void* d_out, int out_size, void* d_ws, size_t ws_size,
                              hipStream_t stream) {
    const float* zin = (const float*)d_in[0];
    const float* x2  = (const float*)d_in[1];
    const float* msk = (const float*)d_in[2];
    const float* dmk = (const float*)d_in[3];
    const float* W5  = (const float*)d_in[4];
    const float* U5  = (const float*)d_in[5];
    const float* bi5 = (const float*)d_in[6];
    const float* br5 = (const float*)d_in[7];
    const float* W6  = (const float*)d_in[8];
    const float* U6  = (const float*)d_in[9];
    const float* bi6 = (const float*)d_in[10];
    const float* br6 = (const float*)d_in[11];
    const float* Wd  = (const float*)d_in[12];
    const float* bd  = (const float*)d_in[13];
    float* out = (float*)d_out;

    // ws (u32 units): h5w[4][128][512] | h6w[2][128][512] | cc5 (8 x 128B-spaced)
    u32* h5w = (u32*)d_ws;                 // 1 MB
    u32* h6w = h5w + 262144;               // 512 KB
    u32* cc5 = h6w + 131072;               // 1 KB

    zero_ws_kernel<<<dim3(1538), dim3(256), 0, stream>>>((u32*)d_ws);

    gru_fused<<<dim3(128), dim3(512), 0, stream>>>(
        zin, x2, msk, dmk, W5, U5, bi5, br5, W6, U6, bi6, br6,
        Wd, bd, out, h5w, h6w, cc5);
}

// Round 11
// 3207.082 us; speedup vs baseline: 1.2736x; 1.1004x over previous
//
#include <hip/hip_runtime.h>
#include <hip/hip_bf16.h>

typedef unsigned short u16;
typedef unsigned int u32;
typedef unsigned long long u64;
typedef __attribute__((ext_vector_type(8))) short bf16x8;   // 8 bf16 (4 VGPRs)
typedef __attribute__((ext_vector_type(4))) float f32x4;

#define MFMA(a,b,c) __builtin_amdgcn_mfma_f32_16x16x32_bf16((a),(b),(c),0,0,0)
#define AGENT __HIP_MEMORY_SCOPE_AGENT

// R11 = R8 proven shape (256 wgs x 256 thr, 204 VGPR spill-free, fan-in 16)
//       + poll-first/x-MFMA overlap + straggler-only retry + 4-slot h5/h6.
//  - 128 GRU5 wgs (rg 0..7 x slice 0..15: 16 rows x 32 h-cols) + 128 GRU6 wgs.
//  - h words: u32 = (step_tag<<16)|bf16, relaxed agent-scope atomics.
//    h5[s]/h6[s] at slot s&3, tag s+1 (0 = unwritten; zeroed ws = init state).
//  - WAR: h5 guarded by cc5 >= 16*(t-3) (GRU6 staging progress, 3-step slack);
//    h6 4-slot safe via tag-observation data dependency.
//  - GRU5 t=0..511 -> h5[t]; GRU6 t=1..513 -> h6[t-1] (t<=512), dec[t-2] (t>=2).

__device__ __forceinline__ u16 f2bf(float f) {
    u32 u = __float_as_uint(f);
    u32 r = (u + 0x7fffu + ((u >> 16) & 1u)) >> 16;
    return (u16)r;
}
__device__ __forceinline__ float bf2f(u16 v) { return __uint_as_float(((u32)v) << 16); }
__device__ __forceinline__ float sat01(float x) { return fminf(1.f, fmaxf(0.f, x)); }
__device__ __forceinline__ float ftanh(float x) {
    x = fminf(10.f, fmaxf(-10.f, x));
    float e = __expf(2.f * x);
    return (e - 1.f) / (e + 1.f);
}

__device__ __forceinline__ bf16x8 loadB(const float* __restrict__ M, int k0, int colbase,
                                        int l15, int q8) {
    const float* p = M + (size_t)(k0 + q8) * 1536 + colbase + l15;
    bf16x8 r;
#pragma unroll
    for (int j = 0; j < 8; ++j) r[j] = (short)f2bf(p[(size_t)j * 1536]);
    return r;
}

__device__ __forceinline__ bf16x8 ldsA(const u16* s, int stride, int colbase, int l15, int q8) {
    return *(const bf16x8*)(s + l15 * stride + colbase + q8);
}

__global__ void zero_ws_kernel(u32* ws) {
    int i = blockIdx.x * 256 + threadIdx.x;
    if (i < 524544) ws[i] = 0u;  // h5w[4][128][512] + h6w[4][128][512] + cc5
}

__global__ void __launch_bounds__(256, 1)
gru_fused(const float* __restrict__ zin, const float* __restrict__ x2,
          const float* __restrict__ msk, const float* __restrict__ dmsk,
          const float* __restrict__ W5, const float* __restrict__ U5,
          const float* __restrict__ bi5, const float* __restrict__ br5,
          const float* __restrict__ W6, const float* __restrict__ U6,
          const float* __restrict__ bi6, const float* __restrict__ br6,
          const float* __restrict__ Wd, const float* __restrict__ bdp,
          float* __restrict__ out, u32* __restrict__ h5w,
          u32* __restrict__ h6w, u32* __restrict__ cc5)
{
    const int wg = blockIdx.x;
    const bool is6 = wg >= 128;
    const int id = is6 ? wg - 128 : wg;
    const int slice = id & 15;          // 16 col-slices of 32 h-cols
    const int rgp = id >> 4;            // 8 rowgroups of 16 batch rows
    const int row0 = rgp << 4;
    const int sb = slice << 5;          // h-col base
    const int tid = threadIdx.x;
    const int wv = tid >> 6, lane = tid & 63;
    const int l15 = lane & 15, q8 = (lane >> 4) << 3;

    __shared__ u16 stg[16 * 1032];
    __shared__ float exch[8 * 16 * 17];

    const int ct = wv & 1;
    const int gMain = (wv < 2) ? 0 : 1;
    const int colMain = gMain * 512 + sb + ct * 16;
    const int colH = 1024 + sb + ct * 16;

    const float* bi = is6 ? bi6 : bi5;
    const float* br = is6 ? br6 : br5;
    const float biasM = bi[colMain + l15] + br[colMain + l15];
    const float biasS = (wv < 2) ? bi[colH + l15] : br[colH + l15];

    bf16x8 Bm[32], Bs[16];
    if (!is6) {
#pragma unroll
        for (int kt = 0; kt < 10; ++kt) Bm[kt] = loadB(W5, kt * 32, colMain, l15, q8);
#pragma unroll
        for (int kt = 0; kt < 16; ++kt) Bm[10 + kt] = loadB(U5, kt * 32, colMain, l15, q8);
        if (wv < 2) {
#pragma unroll
            for (int kt = 0; kt < 10; ++kt) Bs[kt] = loadB(W5, kt * 32, colH, l15, q8);
        } else {
#pragma unroll
            for (int kt = 0; kt < 16; ++kt) Bs[kt] = loadB(U5, kt * 32, colH, l15, q8);
        }
    } else {
#pragma unroll
        for (int kt = 0; kt < 16; ++kt) Bm[kt] = loadB(W6, kt * 32, colMain, l15, q8);
#pragma unroll
        for (int kt = 0; kt < 16; ++kt) Bm[16 + kt] = loadB(U6, kt * 32, colMain, l15, q8);
        if (wv < 2) {
#pragma unroll
            for (int kt = 0; kt < 16; ++kt) Bs[kt] = loadB(W6, kt * 32, colH, l15, q8);
        } else {
#pragma unroll
            for (int kt = 0; kt < 16; ++kt) Bs[kt] = loadB(U6, kt * 32, colH, l15, q8);
        }
    }

    float wdv[8]; float bdv = 0.f;
    if (is6 && wv == 0) {
#pragma unroll
        for (int j = 0; j < 8; ++j) wdv[j] = Wd[lane * 8 + j];
        bdv = bdp[0];
    }

    float hold0 = 0.f, hold1 = 0.f;
    const int grow = tid >> 4, cp = tid & 15;
    const int c2p = cp >> 3, ccb = (cp & 7) * 2;

    const int r_ = tid >> 4, cth = tid & 15;
    const int b_ = row0 + r_;

    if (!is6) {
        // ================= GRU5: t = 0..511, produce h5[t] =================
        for (int t = 0; t < 512; ++t) {
            // ---- issue h5[t-1] poll loads first (slot (t-1)&3, tag t) ----
            const u64* src = (const u64*)(h5w + ((t + 3) & 3) * 65536) + (size_t)b_ * 256;
            const u32 exp = (u32)t;
            u64 v[16];
#pragma unroll
            for (int k = 0; k < 16; ++k)
                v[k] = __hip_atomic_load(&src[cth + 16 * k], __ATOMIC_RELAXED, AGENT);
            // ---- stage masked x under the poll latency ----
            float mk = msk[b_ * 512 + t];
            for (int c = cth; c < 320; c += 16) {
                float xv = (c < 256) ? zin[b_ * 256 + c]
                                     : x2[(b_ * 512 + t) * 64 + (c - 256)];
                stg[r_ * 840 + c] = f2bf(xv * mk);
            }
            __syncthreads();                       // S1: x staged
            // ---- x-part MFMAs (h-independent, K=320) ----
            f32x4 a0 = {biasM, biasM, biasM, biasM};
            f32x4 a1 = {biasS, biasS, biasS, biasS};
            if (wv < 2) {
#pragma unroll
                for (int kt = 0; kt < 10; ++kt) {
                    bf16x8 a = ldsA(stg, 840, kt * 32, l15, q8);
                    a0 = MFMA(a, Bm[kt], a0);
                    a1 = MFMA(a, Bs[kt], a1);
                }
            } else {
#pragma unroll
                for (int kt = 0; kt < 10; ++kt) {
                    bf16x8 a = ldsA(stg, 840, kt * 32, l15, q8);
                    a0 = MFMA(a, Bm[kt], a0);
                }
            }
            // ---- tag check; straggler-only re-poll; stage h ----
#pragma unroll
            for (int k = 0; k < 16; ++k) {
                u32 lo = (u32)v[k], hi = (u32)(v[k] >> 32);
                while (((lo >> 16) != exp) | ((hi >> 16) != exp)) {
                    __builtin_amdgcn_s_sleep(1);
                    u64 nv = __hip_atomic_load(&src[cth + 16 * k], __ATOMIC_RELAXED, AGENT);
                    lo = (u32)nv; hi = (u32)(nv >> 32);
                }
                *(u32*)&stg[r_ * 840 + 320 + 2 * (cth + 16 * k)] = (lo & 0xffffu) | (hi << 16);
            }
            __syncthreads();                       // S2: h staged
            // ---- h-part MFMAs (K=512) ----
            if (wv < 2) {
#pragma unroll
                for (int kt = 0; kt < 16; ++kt) {
                    bf16x8 a = ldsA(stg, 840, 320 + kt * 32, l15, q8);
                    a0 = MFMA(a, Bm[10 + kt], a0);
                }
            } else {
#pragma unroll
                for (int kt = 0; kt < 16; ++kt) {
                    bf16x8 a = ldsA(stg, 840, 320 + kt * 32, l15, q8);
                    a0 = MFMA(a, Bm[10 + kt], a0);
                    a1 = MFMA(a, Bs[kt], a1);
                }
            }
            {
                int uM = gMain * 2 + ct, uS = (wv < 2 ? 4 + ct : 6 + ct);
#pragma unroll
                for (int i = 0; i < 4; ++i) {
                    int rr = (lane >> 4) * 4 + i;
                    exch[uM * 272 + rr * 17 + l15] = a0[i];
                    exch[uS * 272 + rr * 17 + l15] = a1[i];
                }
            }
            __syncthreads();                       // S3: exch ready
            {
                int base0 = (0 + c2p) * 272 + grow * 17 + ccb;
                int base1 = (2 + c2p) * 272 + grow * 17 + ccb;
                int base2 = (4 + c2p) * 272 + grow * 17 + ccb;
                int base3 = (6 + c2p) * 272 + grow * 17 + ccb;
                float zv0 = exch[base0], zv1 = exch[base0 + 1];
                float rv0 = exch[base1], rv1 = exch[base1 + 1];
                float xh0 = exch[base2], xh1 = exch[base2 + 1];
                float ih0 = exch[base3], ih1 = exch[base3 + 1];
                float zg0 = sat01(0.2f * zv0 + 0.5f), zg1 = sat01(0.2f * zv1 + 0.5f);
                float rt0 = sat01(0.2f * rv0 + 0.5f), rt1 = sat01(0.2f * rv1 + 0.5f);
                float hh0 = ftanh(xh0 + rt0 * ih0), hh1 = ftanh(xh1 + rt1 * ih1);
                float h0 = zg0 * hold0 + (1.f - zg0) * hh0;
                float h1 = zg1 * hold1 + (1.f - zg1) * hh1;
                hold0 = h0; hold1 = h1;
                if (t >= 4) {   // 4 slots: GRU6 must have staged h5[t-3]
                    const u32 need = 16u * (u32)(t - 3);
                    while (__hip_atomic_load(&cc5[rgp * 32], __ATOMIC_RELAXED, AGENT) < need)
                        __builtin_amdgcn_s_sleep(1);
                }
                const u32 tg = (u32)(t + 1) << 16;
                u64 w = ((u64)(tg | (u32)f2bf(h1)) << 32) | (u64)(tg | (u32)f2bf(h0));
                u64* dst = (u64*)(h5w + (t & 3) * 65536);
                __hip_atomic_store(&dst[((row0 + grow) * 512 + sb + cp * 2) >> 1], w,
                                   __ATOMIC_RELAXED, AGENT);
            }
        }
    } else {
        // ============ GRU6: t = 1..513, produce h6[t-1], dec[t-2] ============
        for (int t = 1; t <= 513; ++t) {
            // ---- poll h6[t-2] first (old, usually ready): slot (t+2)&3, tag t-1 ----
            {
                const u64* s2 = (const u64*)(h6w + ((t + 2) & 3) * 65536) + (size_t)b_ * 256;
                const u32 exp2 = (u32)(t - 1);
                u64 v[16];
#pragma unroll
                for (int k = 0; k < 16; ++k)
                    v[k] = __hip_atomic_load(&s2[cth + 16 * k], __ATOMIC_RELAXED, AGENT);
#pragma unroll
                for (int k = 0; k < 16; ++k) {
                    u32 lo = (u32)v[k], hi = (u32)(v[k] >> 32);
                    while (((lo >> 16) != exp2) | ((hi >> 16) != exp2)) {
                        __builtin_amdgcn_s_sleep(1);
                        u64 nv = __hip_atomic_load(&s2[cth + 16 * k], __ATOMIC_RELAXED, AGENT);
                        lo = (u32)nv; hi = (u32)(nv >> 32);
                    }
                    *(u32*)&stg[r_ * 1032 + 512 + 2 * (cth + 16 * k)] =
                        (lo & 0xffffu) | (hi << 16);
                }
            }
            // ---- poll g5 = h5[t-1] (fresh): slot (t+3)&3, tag t ----
            if (t <= 512) {
                const u64* s1 = (const u64*)(h5w + ((t + 3) & 3) * 65536) + (size_t)b_ * 256;
                const u32 exp1 = (u32)t;
                u64 v[16];
#pragma unroll
                for (int k = 0; k < 16; ++k)
                    v[k] = __hip_atomic_load(&s1[cth + 16 * k], __ATOMIC_RELAXED, AGENT);
#pragma unroll
                for (int k = 0; k < 16; ++k) {
                    u32 lo = (u32)v[k], hi = (u32)(v[k] >> 32);
                    while (((lo >> 16) != exp1) | ((hi >> 16) != exp1)) {
                        __builtin_amdgcn_s_sleep(1);
                        u64 nv = __hip_atomic_load(&s1[cth + 16 * k], __ATOMIC_RELAXED, AGENT);
                        lo = (u32)nv; hi = (u32)(nv >> 32);
                    }
                    *(u32*)&stg[r_ * 1032 + 2 * (cth + 16 * k)] = (lo & 0xffffu) | (hi << 16);
                }
            }
            __syncthreads();
            if (t <= 512 && tid == 0)   // consumption signal: h5[t-1] staged
                __hip_atomic_fetch_add(&cc5[rgp * 32], 1u, __ATOMIC_RELAXED, AGENT);
            if (t <= 512) {
                f32x4 a0 = {biasM, biasM, biasM, biasM};
                f32x4 a1 = {biasS, biasS, biasS, biasS};
                if (wv < 2) {
#pragma unroll
                    for (int kt = 0; kt < 16; ++kt) {
                        bf16x8 a = ldsA(stg, 1032, kt * 32, l15, q8);
                        a0 = MFMA(a, Bm[kt], a0);
                        a1 = MFMA(a, Bs[kt], a1);
                    }
#pragma unroll
                    for (int kt = 0; kt < 16; ++kt) {
                        bf16x8 a = ldsA(stg, 1032, 512 + kt * 32, l15, q8);
                        a0 = MFMA(a, Bm[16 + kt], a0);
                    }
                } else {
#pragma unroll
                    for (int kt = 0; kt < 16; ++kt) {
                        bf16x8 a = ldsA(stg, 1032, kt * 32, l15, q8);
                        a0 = MFMA(a, Bm[kt], a0);
                    }
#pragma unroll
                    for (int kt = 0; kt < 16; ++kt) {
                        bf16x8 a = ldsA(stg, 1032, 512 + kt * 32, l15, q8);
                        a0 = MFMA(a, Bm[16 + kt], a0);
                        a1 = MFMA(a, Bs[kt], a1);
                    }
                }
                {
                    int uM = gMain * 2 + ct, uS = (wv < 2 ? 4 + ct : 6 + ct);
#pragma unroll
                    for (int i = 0; i < 4; ++i) {
                        int rr = (lane >> 4) * 4 + i;
                        exch[uM * 272 + rr * 17 + l15] = a0[i];
                        exch[uS * 272 + rr * 17 + l15] = a1[i];
                    }
                }
                __syncthreads();
                {
                    int base0 = (0 + c2p) * 272 + grow * 17 + ccb;
                    int base1 = (2 + c2p) * 272 + grow * 17 + ccb;
                    int base2 = (4 + c2p) * 272 + grow * 17 + ccb;
                    int base3 = (6 + c2p) * 272 + grow * 17 + ccb;
                    float zv0 = exch[base0], zv1 = exch[base0 + 1];
                    float rv0 = exch[base1], rv1 = exch[base1 + 1];
                    float xh0 = exch[base2], xh1 = exch[base2 + 1];
                    float ih0 = exch[base3], ih1 = exch[base3 + 1];
                    float zg0 = sat01(0.2f * zv0 + 0.5f), zg1 = sat01(0.2f * zv1 + 0.5f);
                    float rt0 = sat01(0.2f * rv0 + 0.5f), rt1 = sat01(0.2f * rv1 + 0.5f);
                    float hh0 = ftanh(xh0 + rt0 * ih0), hh1 = ftanh(xh1 + rt1 * ih1);
                    float h0 = zg0 * hold0 + (1.f - zg0) * hh0;
                    float h1 = zg1 * hold1 + (1.f - zg1) * hh1;
                    hold0 = h0; hold1 = h1;
                    const u32 tg = (u32)t << 16;   // h6[t-1]: slot (t-1)&3, tag t
                    u64 w = ((u64)(tg | (u32)f2bf(h1)) << 32) | (u64)(tg | (u32)f2bf(h0));
                    u64* dst = (u64*)(h6w + ((t + 3) & 3) * 65536);
                    __hip_atomic_store(&dst[((row0 + grow) * 512 + sb + cp * 2) >> 1], w,
                                       __ATOMIC_RELAXED, AGENT);
                }
            }
            // dec[t-2] from staged h6[t-2] (wave 0; this wg's slice picks one row)
            if (t >= 2 && wv == 0) {
                const u16* hrow = &stg[slice * 1032 + 512 + lane * 8];
                bf16x8 hv = *(const bf16x8*)hrow;
                float s = 0.f;
#pragma unroll
                for (int j = 0; j < 8; ++j) s += bf2f((u16)hv[j]) * wdv[j];
#pragma unroll
                for (int off = 32; off >= 1; off >>= 1) s += __shfl_down(s, off);
                if (lane == 0) {
                    int bb = row0 + slice, tt = t - 2;
                    out[bb * 512 + tt] = ftanh(s + bdv) * dmsk[bb * 512 + tt];
                }
            }
            __syncthreads();   // protect stg before next iteration's writes
        }
    }
}

extern "C" void kernel_launch(void* const* d_in, const int* in_sizes, int n_in,
                              void* d_out, int out_size, void* d_ws, size_t ws_size,
                              hipStream_t stream) {
    const float* zin = (const float*)d_in[0];
    const float* x2  = (const float*)d_in[1];
    const float* msk = (const float*)d_in[2];
    const float* dmk = (const float*)d_in[3];
    const float* W5  = (const float*)d_in[4];
    const float* U5  = (const float*)d_in[5];
    const float* bi5 = (const float*)d_in[6];
    const float* br5 = (const float*)d_in[7];
    const float* W6  = (const float*)d_in[8];
    const float* U6  = (const float*)d_in[9];
    const float* bi6 = (const float*)d_in[10];
    const float* br6 = (const float*)d_in[11];
    const float* Wd  = (const float*)d_in[12];
    const float* bd  = (const float*)d_in[13];
    float* out = (float*)d_out;

    // ws (u32 units): h5w[4][128][512] | h6w[4][128][512] | cc5 (8 x 128B-spaced)
    u32* h5w = (u32*)d_ws;                 // 1 MB
    u32* h6w = h5w + 262144;               // 1 MB
    u32* cc5 = h6w + 262144;               // 1 KB

    zero_ws_kernel<<<dim3(2049), dim3(256), 0, stream>>>((u32*)d_ws);

    gru_fused<<<dim3(256), dim3(256), 0, stream>>>(
        zin, x2, msk, dmk, W5, U5, bi5, br5, W6, U6, bi6, br6,
        Wd, bd, out, h5w, h6w, cc5);
}

// Round 12
// 2577.451 us; speedup vs baseline: 1.5848x; 1.2443x over previous
//
#include <hip/hip_runtime.h>
#include <hip/hip_bf16.h>

typedef unsigned short u16;
typedef unsigned int u32;
typedef unsigned long long u64;
typedef __attribute__((ext_vector_type(8))) short bf16x8;   // 8 bf16 (4 VGPRs)
typedef __attribute__((ext_vector_type(4))) float f32x4;

#define MFMA(a,b,c) __builtin_amdgcn_mfma_f32_16x16x32_bf16((a),(b),(c),0,0,0)
#define AGENT __HIP_MEMORY_SCOPE_AGENT

// R12 = R8 core (256 wgs x 256 thr, bulk-parallel tag polling) +
//  (a) z@W5 precomputed once into persistent f32x4 accumulators (RepeatVector
//      input is t-invariant; mask is a per-(b,t) scalar => bilinear factoring):
//      per-step GRU5 gate = bias + mk*(zacc) + (x2*mk)@W + h@U. K 832->576.
//  (b) 4-slot h5/h6, per-thread rare WAR check (no per-step barrier+spin).
//  (c) 2 barriers per step in BOTH layers (dec moved before exch barrier).
//  (d) XCD swizzle: rowgroup = wg&7 -> all 32 communicating wgs of a rowgroup
//      on one XCD under round-robin dispatch (perf heuristic only).
// Sync protocol: h words u32 = (tag<<16)|bf16, relaxed agent atomics;
// tag = step+1 (0 = initial zero state). Bulk retry rounds (all 16 u64 loads
// in flight per round). h5[s]/h6[s] at slot s&3.
// GRU5 t=0..511 -> h5[t]; GRU6 t=1..513 -> h6[t-1] (t<=512), dec[t-2] (t>=2).

__device__ __forceinline__ u16 f2bf(float f) {
    u32 u = __float_as_uint(f);
    u32 r = (u + 0x7fffu + ((u >> 16) & 1u)) >> 16;
    return (u16)r;
}
__device__ __forceinline__ float bf2f(u16 v) { return __uint_as_float(((u32)v) << 16); }
__device__ __forceinline__ float sat01(float x) { return fminf(1.f, fmaxf(0.f, x)); }
__device__ __forceinline__ float ftanh(float x) {
    x = fminf(10.f, fmaxf(-10.f, x));
    float e = __expf(2.f * x);
    return (e - 1.f) / (e + 1.f);
}

__device__ __forceinline__ bf16x8 loadB(const float* __restrict__ M, int k0, int colbase,
                                        int l15, int q8) {
    const float* p = M + (size_t)(k0 + q8) * 1536 + colbase + l15;
    bf16x8 r;
#pragma unroll
    for (int j = 0; j < 8; ++j) r[j] = (short)f2bf(p[(size_t)j * 1536]);
    return r;
}

__device__ __forceinline__ bf16x8 ldsA(const u16* s, int stride, int colbase, int l15, int q8) {
    return *(const bf16x8*)(s + l15 * stride + colbase + q8);
}

__global__ void zero_ws_kernel(u32* ws) {
    int i = blockIdx.x * 256 + threadIdx.x;
    if (i < 524544) ws[i] = 0u;  // h5w[4][128][512] + h6w[4][128][512] + cc5
}

__global__ void __launch_bounds__(256, 1)
gru_fused(const float* __restrict__ zin, const float* __restrict__ x2,
          const float* __restrict__ msk, const float* __restrict__ dmsk,
          const float* __restrict__ W5, const float* __restrict__ U5,
          const float* __restrict__ bi5, const float* __restrict__ br5,
          const float* __restrict__ W6, const float* __restrict__ U6,
          const float* __restrict__ bi6, const float* __restrict__ br6,
          const float* __restrict__ Wd, const float* __restrict__ bdp,
          float* __restrict__ out, u32* __restrict__ h5w,
          u32* __restrict__ h6w, u32* __restrict__ cc5)
{
    const int wg = blockIdx.x;
    const int rgp = wg & 7;            // rowgroup -> XCD under round-robin
    const int q = wg >> 3;             // 0..31 within rowgroup
    const bool is6 = q >= 16;
    const int slice = q & 15;          // 16 col-slices of 32 h-cols
    const int row0 = rgp << 4;
    const int sb = slice << 5;
    const int tid = threadIdx.x;
    const int wv = tid >> 6, lane = tid & 63;
    const int l15 = lane & 15, q8 = (lane >> 4) << 3;

    __shared__ u16 stg[16 * 1032];     // GRU5 stride 584 (64 x2 | 512 h); GRU6 stride 1032
    __shared__ float exch[8 * 272];
    __shared__ float mkl[16];

    const int ct = wv & 1;
    const int gMain = (wv < 2) ? 0 : 1;
    const int colMain = gMain * 512 + sb + ct * 16;
    const int colH = 1024 + sb + ct * 16;

    const float* bi = is6 ? bi6 : bi5;
    const float* br = is6 ? br6 : br5;
    const float biasM = bi[colMain + l15] + br[colMain + l15];
    const float biasS = (wv < 2) ? bi[colH + l15] : br[colH + l15];

    float hold0 = 0.f, hold1 = 0.f;
    const int grow = tid >> 4, cp = tid & 15;
    const int c2p = cp >> 3, ccb = (cp & 7) * 2;
    const int r_ = tid >> 4, cth = tid & 15;
    const int b_ = row0 + r_;

    float wdv[8]; float bdv = 0.f;

    if (!is6) {
        // ---- persistent B fragments: x2-part (W5 rows 256..319) + h-part (U5) ----
        bf16x8 Bx[2], Bxs[2], Bh[16], Bhs[16];
#pragma unroll
        for (int kt = 0; kt < 2; ++kt) Bx[kt] = loadB(W5, 256 + kt * 32, colMain, l15, q8);
#pragma unroll
        for (int kt = 0; kt < 16; ++kt) Bh[kt] = loadB(U5, kt * 32, colMain, l15, q8);
        if (wv < 2) {
#pragma unroll
            for (int kt = 0; kt < 2; ++kt) Bxs[kt] = loadB(W5, 256 + kt * 32, colH, l15, q8);
        } else {
#pragma unroll
            for (int kt = 0; kt < 16; ++kt) Bhs[kt] = loadB(U5, kt * 32, colH, l15, q8);
        }

        // ---- one-time z@W5 precompute (unmasked z; mask folded in per step) ----
        for (int c = cth; c < 256; c += 16) stg[r_ * 584 + c] = f2bf(zin[b_ * 256 + c]);
        __syncthreads();
        f32x4 zaccM = {0.f, 0.f, 0.f, 0.f}, zaccS = {0.f, 0.f, 0.f, 0.f};
        for (int kt = 0; kt < 8; ++kt) {
            bf16x8 a = ldsA(stg, 584, kt * 32, l15, q8);
            bf16x8 bz = loadB(W5, kt * 32, colMain, l15, q8);
            zaccM = MFMA(a, bz, zaccM);
            if (wv < 2) {
                bf16x8 bz2 = loadB(W5, kt * 32, colH, l15, q8);
                zaccS = MFMA(a, bz2, zaccS);
            }
        }
        __syncthreads();

        // ================= GRU5: t = 0..511, produce h5[t] =================
        for (int t = 0; t < 512; ++t) {
            // ---- issue h5[t-1] poll loads first (slot (t-1)&3, tag t) ----
            const u64* src = (const u64*)(h5w + ((t + 3) & 3) * 65536) + (size_t)b_ * 256;
            const u32 exp = (u32)t;
            u64 v[16];
#pragma unroll
            for (int k = 0; k < 16; ++k)
                v[k] = __hip_atomic_load(&src[cth + 16 * k], __ATOMIC_RELAXED, AGENT);
            // ---- stage x2*mk (64 cols) + mkl under poll latency ----
            float mk = msk[b_ * 512 + t];
#pragma unroll
            for (int i = 0; i < 4; ++i) {
                int c = cth + 16 * i;
                stg[r_ * 584 + c] = f2bf(x2[(b_ * 512 + t) * 64 + c] * mk);
            }
            if (tid < 16) mkl[tid] = msk[(row0 + tid) * 512 + t];
            // ---- bulk tag check / bulk retry ----
            for (;;) {
                bool ok = true;
#pragma unroll
                for (int k = 0; k < 16; ++k) {
                    u32 lo = (u32)v[k], hi = (u32)(v[k] >> 32);
                    if (((lo >> 16) != exp) | ((hi >> 16) != exp)) ok = false;
                }
                if (ok) break;
                __builtin_amdgcn_s_sleep(1);
#pragma unroll
                for (int k = 0; k < 16; ++k)
                    v[k] = __hip_atomic_load(&src[cth + 16 * k], __ATOMIC_RELAXED, AGENT);
            }
#pragma unroll
            for (int k = 0; k < 16; ++k) {
                u32 lo = (u32)v[k], hi = (u32)(v[k] >> 32);
                *(u32*)&stg[r_ * 584 + 64 + 2 * (cth + 16 * k)] = (lo & 0xffffu) | (hi << 16);
            }
            __syncthreads();                       // S1: staged
            // ---- MFMA: init = bias + mk*zacc ; x2 (2 kt) + h (16 kt) ----
            float mkr[4];
#pragma unroll
            for (int i = 0; i < 4; ++i) mkr[i] = mkl[(lane >> 4) * 4 + i];
            f32x4 a0, a1;
#pragma unroll
            for (int i = 0; i < 4; ++i) a0[i] = biasM + mkr[i] * zaccM[i];
            if (wv < 2) {
#pragma unroll
                for (int i = 0; i < 4; ++i) a1[i] = biasS + mkr[i] * zaccS[i];
#pragma unroll
                for (int kt = 0; kt < 2; ++kt) {
                    bf16x8 a = ldsA(stg, 584, kt * 32, l15, q8);
                    a0 = MFMA(a, Bx[kt], a0);
                    a1 = MFMA(a, Bxs[kt], a1);
                }
#pragma unroll
                for (int kt = 0; kt < 16; ++kt) {
                    bf16x8 a = ldsA(stg, 584, 64 + kt * 32, l15, q8);
                    a0 = MFMA(a, Bh[kt], a0);
                }
            } else {
#pragma unroll
                for (int i = 0; i < 4; ++i) a1[i] = biasS;
#pragma unroll
                for (int kt = 0; kt < 2; ++kt) {
                    bf16x8 a = ldsA(stg, 584, kt * 32, l15, q8);
                    a0 = MFMA(a, Bx[kt], a0);
                }
#pragma unroll
                for (int kt = 0; kt < 16; ++kt) {
                    bf16x8 a = ldsA(stg, 584, 64 + kt * 32, l15, q8);
                    a0 = MFMA(a, Bh[kt], a0);
                    a1 = MFMA(a, Bhs[kt], a1);
                }
            }
            {
                int uM = gMain * 2 + ct, uS = (wv < 2 ? 4 + ct : 6 + ct);
#pragma unroll
                for (int i = 0; i < 4; ++i) {
                    int rr = (lane >> 4) * 4 + i;
                    exch[uM * 272 + rr * 17 + l15] = a0[i];
                    exch[uS * 272 + rr * 17 + l15] = a1[i];
                }
            }
            __syncthreads();                       // S2: exch ready
            {
                int base0 = (0 + c2p) * 272 + grow * 17 + ccb;
                int base1 = (2 + c2p) * 272 + grow * 17 + ccb;
                int base2 = (4 + c2p) * 272 + grow * 17 + ccb;
                int base3 = (6 + c2p) * 272 + grow * 17 + ccb;
                float zv0 = exch[base0], zv1 = exch[base0 + 1];
                float rv0 = exch[base1], rv1 = exch[base1 + 1];
                float xh0 = exch[base2], xh1 = exch[base2 + 1];
                float ih0 = exch[base3], ih1 = exch[base3 + 1];
                float zg0 = sat01(0.2f * zv0 + 0.5f), zg1 = sat01(0.2f * zv1 + 0.5f);
                float rt0 = sat01(0.2f * rv0 + 0.5f), rt1 = sat01(0.2f * rv1 + 0.5f);
                float hh0 = ftanh(xh0 + rt0 * ih0), hh1 = ftanh(xh1 + rt1 * ih1);
                float h0 = zg0 * hold0 + (1.f - zg0) * hh0;
                float h1 = zg1 * hold1 + (1.f - zg1) * hh1;
                hold0 = h0; hold1 = h1;
                if (t >= 4) {   // 4 slots: GRU6 must have staged h5[t-3]; rare spin
                    const u32 need = 16u * (u32)(t - 3);
                    while (__hip_atomic_load(&cc5[rgp * 32], __ATOMIC_RELAXED, AGENT) < need)
                        __builtin_amdgcn_s_sleep(1);
                }
                const u32 tg = (u32)(t + 1) << 16;
                u64 w = ((u64)(tg | (u32)f2bf(h1)) << 32) | (u64)(tg | (u32)f2bf(h0));
                u64* dst = (u64*)(h5w + (t & 3) * 65536);
                __hip_atomic_store(&dst[((row0 + grow) * 512 + sb + cp * 2) >> 1], w,
                                   __ATOMIC_RELAXED, AGENT);
            }
        }
    } else {
        // ---- persistent B fragments for GRU6 ----
        bf16x8 Bm[32], Bs[16];
#pragma unroll
        for (int kt = 0; kt < 16; ++kt) Bm[kt] = loadB(W6, kt * 32, colMain, l15, q8);
#pragma unroll
        for (int kt = 0; kt < 16; ++kt) Bm[16 + kt] = loadB(U6, kt * 32, colMain, l15, q8);
        if (wv < 2) {
#pragma unroll
            for (int kt = 0; kt < 16; ++kt) Bs[kt] = loadB(W6, kt * 32, colH, l15, q8);
        } else {
#pragma unroll
            for (int kt = 0; kt < 16; ++kt) Bs[kt] = loadB(U6, kt * 32, colH, l15, q8);
        }
        if (wv == 0) {
#pragma unroll
            for (int j = 0; j < 8; ++j) wdv[j] = Wd[lane * 8 + j];
            bdv = bdp[0];
        }

        // ============ GRU6: t = 1..513, produce h6[t-1], dec[t-2] ============
        for (int t = 1; t <= 513; ++t) {
            const u64* s2 = (const u64*)(h6w + ((t + 2) & 3) * 65536) + (size_t)b_ * 256;
            const u32 exp2 = (u32)(t - 1);
            if (t <= 512) {
                const u64* s1 = (const u64*)(h5w + ((t + 3) & 3) * 65536) + (size_t)b_ * 256;
                const u32 exp1 = (u32)t;
                u64 v1[16], v2[16];
#pragma unroll
                for (int k = 0; k < 16; ++k) {
                    v1[k] = __hip_atomic_load(&s1[cth + 16 * k], __ATOMIC_RELAXED, AGENT);
                    v2[k] = __hip_atomic_load(&s2[cth + 16 * k], __ATOMIC_RELAXED, AGENT);
                }
                for (;;) {
                    bool ok = true;
#pragma unroll
                    for (int k = 0; k < 16; ++k) {
                        u32 lo1 = (u32)v1[k], hi1 = (u32)(v1[k] >> 32);
                        u32 lo2 = (u32)v2[k], hi2 = (u32)(v2[k] >> 32);
                        if (((lo1 >> 16) != exp1) | ((hi1 >> 16) != exp1) |
                            ((lo2 >> 16) != exp2) | ((hi2 >> 16) != exp2)) ok = false;
                    }
                    if (ok) break;
                    __builtin_amdgcn_s_sleep(1);
#pragma unroll
                    for (int k = 0; k < 16; ++k) {
                        v1[k] = __hip_atomic_load(&s1[cth + 16 * k], __ATOMIC_RELAXED, AGENT);
                        v2[k] = __hip_atomic_load(&s2[cth + 16 * k], __ATOMIC_RELAXED, AGENT);
                    }
                }
#pragma unroll
                for (int k = 0; k < 16; ++k) {
                    u32 lo = (u32)v1[k], hi = (u32)(v1[k] >> 32);
                    *(u32*)&stg[r_ * 1032 + 2 * (cth + 16 * k)] = (lo & 0xffffu) | (hi << 16);
                    lo = (u32)v2[k]; hi = (u32)(v2[k] >> 32);
                    *(u32*)&stg[r_ * 1032 + 512 + 2 * (cth + 16 * k)] = (lo & 0xffffu) | (hi << 16);
                }
            } else {
                u64 v2[16];
#pragma unroll
                for (int k = 0; k < 16; ++k)
                    v2[k] = __hip_atomic_load(&s2[cth + 16 * k], __ATOMIC_RELAXED, AGENT);
                for (;;) {
                    bool ok = true;
#pragma unroll
                    for (int k = 0; k < 16; ++k) {
                        u32 lo = (u32)v2[k], hi = (u32)(v2[k] >> 32);
                        if (((lo >> 16) != exp2) | ((hi >> 16) != exp2)) ok = false;
                    }
                    if (ok) break;
                    __builtin_amdgcn_s_sleep(1);
#pragma unroll
                    for (int k = 0; k < 16; ++k)
                        v2[k] = __hip_atomic_load(&s2[cth + 16 * k], __ATOMIC_RELAXED, AGENT);
                }
#pragma unroll
                for (int k = 0; k < 16; ++k) {
                    u32 lo = (u32)v2[k], hi = (u32)(v2[k] >> 32);
                    *(u32*)&stg[r_ * 1032 + 512 + 2 * (cth + 16 * k)] = (lo & 0xffffu) | (hi << 16);
                }
            }
            __syncthreads();                       // S1: staged
            if (t <= 512 && tid == 0)
                __hip_atomic_fetch_add(&cc5[rgp * 32], 1u, __ATOMIC_RELAXED, AGENT);
            f32x4 a0 = {biasM, biasM, biasM, biasM};
            f32x4 a1 = {biasS, biasS, biasS, biasS};
            if (t <= 512) {
                if (wv < 2) {
#pragma unroll
                    for (int kt = 0; kt < 16; ++kt) {
                        bf16x8 a = ldsA(stg, 1032, kt * 32, l15, q8);
                        a0 = MFMA(a, Bm[kt], a0);
                        a1 = MFMA(a, Bs[kt], a1);
                    }
#pragma unroll
                    for (int kt = 0; kt < 16; ++kt) {
                        bf16x8 a = ldsA(stg, 1032, 512 + kt * 32, l15, q8);
                        a0 = MFMA(a, Bm[16 + kt], a0);
                    }
                } else {
#pragma unroll
                    for (int kt = 0; kt < 16; ++kt) {
                        bf16x8 a = ldsA(stg, 1032, kt * 32, l15, q8);
                        a0 = MFMA(a, Bm[kt], a0);
                    }
#pragma unroll
                    for (int kt = 0; kt < 16; ++kt) {
                        bf16x8 a = ldsA(stg, 1032, 512 + kt * 32, l15, q8);
                        a0 = MFMA(a, Bm[16 + kt], a0);
                        a1 = MFMA(a, Bs[kt], a1);
                    }
                }
            }
            // dec[t-2] from staged h6[t-2] (wave 0) — before exch barrier
            if (t >= 2 && wv == 0) {
                const u16* hrow = &stg[slice * 1032 + 512 + lane * 8];
                bf16x8 hv = *(const bf16x8*)hrow;
                float s = 0.f;
#pragma unroll
                for (int j = 0; j < 8; ++j) s += bf2f((u16)hv[j]) * wdv[j];
#pragma unroll
                for (int off = 32; off >= 1; off >>= 1) s += __shfl_down(s, off);
                if (lane == 0) {
                    int bb = row0 + slice, tt = t - 2;
                    out[bb * 512 + tt] = ftanh(s + bdv) * dmsk[bb * 512 + tt];
                }
            }
            if (t <= 512) {
                {
                    int uM = gMain * 2 + ct, uS = (wv < 2 ? 4 + ct : 6 + ct);
#pragma unroll
                    for (int i = 0; i < 4; ++i) {
                        int rr = (lane >> 4) * 4 + i;
                        exch[uM * 272 + rr * 17 + l15] = a0[i];
                        exch[uS * 272 + rr * 17 + l15] = a1[i];
                    }
                }
                __syncthreads();                   // S2: exch ready
                {
                    int base0 = (0 + c2p) * 272 + grow * 17 + ccb;
                    int base1 = (2 + c2p) * 272 + grow * 17 + ccb;
                    int base2 = (4 + c2p) * 272 + grow * 17 + ccb;
                    int base3 = (6 + c2p) * 272 + grow * 17 + ccb;
                    float zv0 = exch[base0], zv1 = exch[base0 + 1];
                    float rv0 = exch[base1], rv1 = exch[base1 + 1];
                    float xh0 = exch[base2], xh1 = exch[base2 + 1];
                    float ih0 = exch[base3], ih1 = exch[base3 + 1];
                    float zg0 = sat01(0.2f * zv0 + 0.5f), zg1 = sat01(0.2f * zv1 + 0.5f);
                    float rt0 = sat01(0.2f * rv0 + 0.5f), rt1 = sat01(0.2f * rv1 + 0.5f);
                    float hh0 = ftanh(xh0 + rt0 * ih0), hh1 = ftanh(xh1 + rt1 * ih1);
                    float h0 = zg0 * hold0 + (1.f - zg0) * hh0;
                    float h1 = zg1 * hold1 + (1.f - zg1) * hh1;
                    hold0 = h0; hold1 = h1;
                    const u32 tg = (u32)t << 16;   // h6[t-1]: slot (t-1)&3, tag t
                    u64 w = ((u64)(tg | (u32)f2bf(h1)) << 32) | (u64)(tg | (u32)f2bf(h0));
                    u64* dst = (u64*)(h6w + ((t + 3) & 3) * 65536);
                    __hip_atomic_store(&dst[((row0 + grow) * 512 + sb + cp * 2) >> 1], w,
                                       __ATOMIC_RELAXED, AGENT);
                }
            } else {
                __syncthreads();                   // keep barrier count uniform at t=513
            }
        }
    }
}

extern "C" void kernel_launch(void* const* d_in, const int* in_sizes, int n_in,
                              void* d_out, int out_size, void* d_ws, size_t ws_size,
                              hipStream_t stream) {
    const float* zin = (const float*)d_in[0];
    const float* x2  = (const float*)d_in[1];
    const float* msk = (const float*)d_in[2];
    const float* dmk = (const float*)d_in[3];
    const float* W5  = (const float*)d_in[4];
    const float* U5  = (const float*)d_in[5];
    const float* bi5 = (const float*)d_in[6];
    const float* br5 = (const float*)d_in[7];
    const float* W6  = (const float*)d_in[8];
    const float* U6  = (const float*)d_in[9];
    const float* bi6 = (const float*)d_in[10];
    const float* br6 = (const float*)d_in[11];
    const float* Wd  = (const float*)d_in[12];
    const float* bd  = (const float*)d_in[13];
    float* out = (float*)d_out;

    // ws (u32 units): h5w[4][128][512] | h6w[4][128][512] | cc5 (8 x 128B-spaced)
    u32* h5w = (u32*)d_ws;                 // 1 MB
    u32* h6w = h5w + 262144;               // 1 MB
    u32* cc5 = h6w + 262144;               // 1 KB

    zero_ws_kernel<<<dim3(2049), dim3(256), 0, stream>>>((u32*)d_ws);

    gru_fused<<<dim3(256), dim3(256), 0, stream>>>(
        zin, x2, msk, dmk, W5, U5, bi5, br5, W6, U6, bi6, br6,
        Wd, bd, out, h5w, h6w, cc5);
}